// Round 11
// baseline (170.450 us; speedup 1.0000x reference)
//
#include <hip/hip_runtime.h>
#include <hip/hip_bf16.h>

#define C_DIM 256
#define B_SZ 32
#define NS 4096
#define NT_Z 256
#define TOPK_K 32
#define NWIN 64
#define WTOK 64

typedef __attribute__((ext_vector_type(8))) short short8;
typedef __attribute__((ext_vector_type(4))) float f32x4;

static __device__ inline unsigned short f2b(float f) {
  union { float f; unsigned int u; } x; x.f = f;
  unsigned int u = x.u;
  return (unsigned short)((u + 0x7FFFu + ((u >> 16) & 1u)) >> 16);
}
static __device__ inline float b2f(unsigned int h16) {   // low 16 bits = bf16
  union { unsigned int u; float f; } x; x.u = h16 << 16;
  return x.f;
}

// ---------------- kernel 1: weights f32->bf16 (vectorized) + z_max partials -
__global__ void prep_kernel(const float* __restrict__ Wd, const float* __restrict__ Wu,
                            unsigned short* __restrict__ Wdb, unsigned short* __restrict__ Wub,
                            const float* __restrict__ z, float* __restrict__ zpart) {
  int blk = blockIdx.x;
  if (blk < 64) {
    int i = blk * 256 + threadIdx.x;     // float4 id, 16384 per matrix
    float4 a = ((const float4*)Wd)[i];
    float4 c = ((const float4*)Wu)[i];
    ushort4 ha, hc;
    ha.x = f2b(a.x); ha.y = f2b(a.y); ha.z = f2b(a.z); ha.w = f2b(a.w);
    hc.x = f2b(c.x); hc.y = f2b(c.y); hc.z = f2b(c.z); hc.w = f2b(c.w);
    ((ushort4*)Wdb)[i] = ha;
    ((ushort4*)Wub)[i] = hc;
  } else {
    int i = blk - 64;                    // 0..255
    int b = i >> 3, ch = i & 7;
    int c = threadIdx.x;
    const float* p = z + ((size_t)b * NT_Z + ch * 32) * C_DIM + c;
    float m = p[0];
    for (int n = 1; n < 32; ++n) m = fmaxf(m, p[(size_t)n * C_DIM]);
    zpart[(size_t)i * C_DIM + c] = m;
  }
}

// ---------------- kernel 2: window scores (+ zmax final reduce) -------------
__global__ __launch_bounds__(256) void winscore_kernel(const float* __restrict__ x,
                                                       const float* __restrict__ zpart,
                                                       float* __restrict__ score) {
  int b = blockIdx.x >> 6;
  int w = blockIdx.x & 63;
  int wy = w >> 3, wx = w & 7;

  __shared__ float zs[C_DIM];
  {
    float m = zpart[(size_t)(b * 8) * C_DIM + threadIdx.x];
    #pragma unroll
    for (int ch = 1; ch < 8; ++ch)
      m = fmaxf(m, zpart[(size_t)(b * 8 + ch) * C_DIM + threadIdx.x]);
    zs[threadIdx.x] = m;
  }
  __syncthreads();

  int wv = threadIdx.x >> 6;
  int ln = threadIdx.x & 63;

  float a0 = 0.f, a1 = 0.f, a2 = 0.f, a3 = 0.f;
  for (int t = 0; t < 16; ++t) {
    int tok = wv * 16 + t;
    int iy = tok >> 3, ix = tok & 7;
    int n = (wy * 8 + iy) * 64 + wx * 8 + ix;
    const float4 v = *(const float4*)(x + ((size_t)b * NS + n) * C_DIM + ln * 4);
    a0 += v.x; a1 += v.y; a2 += v.z; a3 += v.w;
  }
  const float4 z4 = ((const float4*)zs)[ln];
  float p = a0 * z4.x + a1 * z4.y + a2 * z4.z + a3 * z4.w;
  for (int off = 32; off >= 1; off >>= 1) p += __shfl_xor(p, off);

  __shared__ float wsum[4];
  if (ln == 0) wsum[wv] = p;
  __syncthreads();
  if (threadIdx.x == 0) score[blockIdx.x] = wsum[0] + wsum[1] + wsum[2] + wsum[3];
}

// ---------------- kernel 3: fused topk + gather + GEMM1 + shift + GEMM2 ----
// SINGLE 32 KB LDS buffer (xe -> t -> out-bf16), 256 thr / 4 waves.
// __launch_bounds__(256,3): 170-reg cap -> 3 waves/SIMD = 12 waves/CU.
// Rolling depth-3 weight prefetch (48 VGPR); residual captured to 32 VGPR and
// folded into acc2 C-init (dies before GEMM2).  Peak ~100 VGPR + 64 AGPR.
// XOR swizzle: byte_in_row ^= (row & 7) << 4.
__global__ __launch_bounds__(256, 3) void fused_win(
    const float* __restrict__ x, const float* __restrict__ score,
    const unsigned short* __restrict__ Wdb, const unsigned short* __restrict__ Wub,
    const float* __restrict__ bd, const float* __restrict__ bu,
    float* __restrict__ out)
{
  __shared__ unsigned short buf[WTOK * C_DIM];  // 32 KB (xe, then t, then sum)
  __shared__ float sc[NWIN];
  __shared__ int wsel_s;

  const int bk = blockIdx.x;
  const int b = bk >> 5;
  const int kk = bk & 31;
  const int tid = threadIdx.x;

  // ---- in-block top-k rank select (reproduces jax.lax.top_k order) ----
  if (tid < NWIN) sc[tid] = score[b * NWIN + tid];
  __syncthreads();
  if (tid < NWIN) {
    float v = sc[tid];
    int rank = 0;
    #pragma unroll
    for (int j = 0; j < NWIN; ++j) {
      float sj = sc[j];
      rank += (sj > v) || (sj == v && j < tid);
    }
    if (rank == kk) wsel_s = tid;
  }
  __syncthreads();
  const int wsel = wsel_s;
  const int wy = wsel >> 3, wx = wsel & 7;

  const int wv = tid >> 6;
  const int ln = tid & 63;
  const int lr = ln & 15;   // A-row / B-col / D-col
  const int lg = ln >> 4;   // k-subgroup
  const int c4 = tid & 63;  // float4 column for staging/output
  const int m0w = tid >> 6; // starting row for staging/output

  const unsigned short* wdbase = Wdb + (size_t)(wv * 64 + lr) * C_DIM + lg * 8;
  const unsigned short* wubase = Wub + (size_t)(wv * 64 + lr) * C_DIM + lg * 8;

  // ---- GEMM1 weight rolling prologue (depth 3, in flight during staging) ----
  short8 wq[3][4];
  #pragma unroll
  for (int p = 0; p < 3; ++p)
    #pragma unroll
    for (int nt = 0; nt < 4; ++nt)
      wq[p][nt] = *(const short8*)(wdbase + nt * 16 * C_DIM + p * 32);

  // bias regs
  float bdv[4], buv[4];
  #pragma unroll
  for (int nt = 0; nt < 4; ++nt) {
    bdv[nt] = bd[wv * 64 + nt * 16 + lr];
    buv[nt] = bu[wv * 64 + nt * 16 + lr];
  }

  // ---- stage xe (bf16, swizzled) in two batches of 8 rows/thread ----
  {
    const float* xb = x + (size_t)b * NS * C_DIM + c4 * 4;
    #pragma unroll
    for (int h = 0; h < 2; ++h) {
      float4 xv[8];
      #pragma unroll
      for (int i = 0; i < 8; ++i) {
        int m = m0w + (h * 8 + i) * 4;
        int n = (wy * 8 + (m >> 3)) * 64 + wx * 8 + (m & 7);
        xv[i] = *(const float4*)(xb + (size_t)n * C_DIM);
      }
      #pragma unroll
      for (int i = 0; i < 8; ++i) {
        int m = m0w + (h * 8 + i) * 4;
        ushort4 hs;
        hs.x = f2b(xv[i].x); hs.y = f2b(xv[i].y); hs.z = f2b(xv[i].z); hs.w = f2b(xv[i].w);
        int byteoff = m * 512 + ((c4 * 8) ^ ((m & 7) << 4));
        *(ushort4*)((char*)buf + byteoff) = hs;
      }
    }
  }
  __syncthreads();   // B1: xe ready

  // ---- GEMM1: t = xe @ Wd^T (rolling weight prefetch) ----
  f32x4 acc[4][4];
  #pragma unroll
  for (int a = 0; a < 4; ++a)
    #pragma unroll
    for (int n2 = 0; n2 < 4; ++n2) acc[a][n2] = (f32x4){0.f, 0.f, 0.f, 0.f};

  #pragma unroll
  for (int ks = 0; ks < 8; ++ks) {
    const int slot = ks % 3;
    const int kb = ks * 64 + lg * 16;
    short8 af[4];
    #pragma unroll
    for (int mt = 0; mt < 4; ++mt) {
      int m = mt * 16 + lr;
      af[mt] = *(const short8*)((const char*)buf + m * 512 + (kb ^ ((m & 7) << 4)));
    }
    __builtin_amdgcn_s_setprio(1);
    #pragma unroll
    for (int mt = 0; mt < 4; ++mt)
      #pragma unroll
      for (int nt = 0; nt < 4; ++nt)
        acc[mt][nt] = __builtin_amdgcn_mfma_f32_16x16x32_bf16(af[mt], wq[slot][nt], acc[mt][nt], 0, 0, 0);
    __builtin_amdgcn_s_setprio(0);
    if (ks + 3 < 8) {
      #pragma unroll
      for (int nt = 0; nt < 4; ++nt)
        wq[slot][nt] = *(const short8*)(wdbase + nt * 16 * C_DIM + (ks + 3) * 32);
    }
  }

  // ---- capture residual xe (MFMA C/D layout) into 32 packed regs ----
  unsigned int res[4][4][2];
  #pragma unroll
  for (int mt = 0; mt < 4; ++mt) {
    #pragma unroll
    for (int nt = 0; nt < 4; ++nt) {
      int c = wv * 64 + nt * 16 + lr;
      #pragma unroll
      for (int j = 0; j < 2; ++j) {
        int m0 = mt * 16 + lg * 4 + 2 * j;
        unsigned int lo = *(const unsigned short*)((const char*)buf + m0 * 512 + ((c * 2) ^ ((m0 & 7) << 4)));
        unsigned int hi = *(const unsigned short*)((const char*)buf + (m0 + 1) * 512 + ((c * 2) ^ (((m0 + 1) & 7) << 4)));
        res[mt][nt][j] = lo | (hi << 16);
      }
    }
  }

  // ---- GEMM2 weight prologue (latency hides under epi1 + barrier) ----
  short8 wq2[3][4];
  #pragma unroll
  for (int p = 0; p < 3; ++p)
    #pragma unroll
    for (int nt = 0; nt < 4; ++nt)
      wq2[p][nt] = *(const short8*)(wubase + nt * 16 * C_DIM + p * 32);

  __syncthreads();   // B2: all xe reads done, buf free for t

  // ---- epi1: t = acc + bd -> bf16 -> buf (swizzled) ----
  #pragma unroll
  for (int nt = 0; nt < 4; ++nt) {
    int o = wv * 64 + nt * 16 + lr;
    #pragma unroll
    for (int mt = 0; mt < 4; ++mt) {
      #pragma unroll
      for (int r = 0; r < 4; ++r) {
        int m = mt * 16 + lg * 4 + r;
        *(unsigned short*)((char*)buf + m * 512 + ((o * 2) ^ ((m & 7) << 4))) = f2b(acc[mt][nt][r] + bdv[nt]);
      }
    }
  }
  __syncthreads();   // B3: t ready

  // ---- acc2 init = xe + bu (res dies here) ----
  f32x4 acc2[4][4];
  #pragma unroll
  for (int mt = 0; mt < 4; ++mt) {
    #pragma unroll
    for (int nt = 0; nt < 4; ++nt) {
      acc2[mt][nt][0] = b2f(res[mt][nt][0] & 0xffffu) + buv[nt];
      acc2[mt][nt][1] = b2f(res[mt][nt][0] >> 16)     + buv[nt];
      acc2[mt][nt][2] = b2f(res[mt][nt][1] & 0xffffu) + buv[nt];
      acc2[mt][nt][3] = b2f(res[mt][nt][1] >> 16)     + buv[nt];
    }
  }

  // ---- GEMM2: acc2 += shift(t) @ Wu^T (rolling weight prefetch) ----
  #pragma unroll
  for (int ks = 0; ks < 8; ++ks) {
    const int slot = ks % 3;
    const int g = ks >> 1;              // channel group (64-wide), uniform per ks
    const int dd = ((g & 1) ? -1 : 1) * ((g & 2) ? 8 : 1);
    const int kb = ks * 64 + lg * 16;
    short8 af[4];
    #pragma unroll
    for (int mt = 0; mt < 4; ++mt) {
      int m = mt * 16 + lr;
      int pos = (g & 2) ? (m >> 3) : (m & 7);
      bool ok = (g & 1) ? (pos > 0) : (pos < 7);
      int ms = m + dd;
      ms = ms < 0 ? 0 : (ms > 63 ? 63 : ms);   // safe address, result masked
      short8 v = *(const short8*)((const char*)buf + ms * 512 + (kb ^ ((ms & 7) << 4)));
      const short8 zed = {0, 0, 0, 0, 0, 0, 0, 0};
      af[mt] = ok ? v : zed;
    }
    __builtin_amdgcn_s_setprio(1);
    #pragma unroll
    for (int mt = 0; mt < 4; ++mt)
      #pragma unroll
      for (int nt = 0; nt < 4; ++nt)
        acc2[mt][nt] = __builtin_amdgcn_mfma_f32_16x16x32_bf16(af[mt], wq2[slot][nt], acc2[mt][nt], 0, 0, 0);
    __builtin_amdgcn_s_setprio(0);
    if (ks + 3 < 8) {
      #pragma unroll
      for (int nt = 0; nt < 4; ++nt)
        wq2[slot][nt] = *(const short8*)(wubase + nt * 16 * C_DIM + (ks + 3) * 32);
    }
  }
  __syncthreads();   // B4: all t reads done, buf free for sum

  // ---- epi2a: buf = f2b(acc2)  (acc2 = xe + up + bu) ----
  #pragma unroll
  for (int nt = 0; nt < 4; ++nt) {
    int c = wv * 64 + nt * 16 + lr;
    #pragma unroll
    for (int mt = 0; mt < 4; ++mt) {
      #pragma unroll
      for (int r = 0; r < 4; ++r) {
        int m = mt * 16 + lg * 4 + r;
        *(unsigned short*)((char*)buf + m * 512 + ((c * 2) ^ ((m & 7) << 4))) = f2b(acc2[mt][nt][r]);
      }
    }
  }
  __syncthreads();   // B5

  // ---- epi2b: coalesced full-row f32 stores ----
  {
    float* ob = out + (size_t)bk * WTOK * C_DIM + c4 * 4;
    #pragma unroll
    for (int i = 0; i < 16; ++i) {
      int m = m0w + i * 4;
      int off = m * 512 + ((c4 * 8) ^ ((m & 7) << 4));
      ushort4 s4 = *(const ushort4*)((const char*)buf + off);
      float4 o;
      o.x = b2f(s4.x); o.y = b2f(s4.y); o.z = b2f(s4.z); o.w = b2f(s4.w);
      *(float4*)(ob + (size_t)m * C_DIM) = o;
    }
  }
}

// ---------------- launch ----------------
extern "C" void kernel_launch(void* const* d_in, const int* in_sizes, int n_in,
                              void* d_out, int out_size, void* d_ws, size_t ws_size,
                              hipStream_t stream) {
  const float* z  = (const float*)d_in[0];
  const float* x  = (const float*)d_in[1];
  const float* Wd = (const float*)d_in[2];
  const float* bd = (const float*)d_in[3];
  const float* Wu = (const float*)d_in[4];
  const float* bu = (const float*)d_in[5];
  float* out = (float*)d_out;

  char* ws = (char*)d_ws;
  unsigned short* Wdb = (unsigned short*)(ws);            // 0      .. 131072
  unsigned short* Wub = (unsigned short*)(ws + 131072);   // 131072 .. 262144
  float* zpart = (float*)(ws + 262144);                   // 262144 .. 524288 (32*8*256 f32)
  float* score = (float*)(ws + 524288);                   // 524288 .. 532480

  hipLaunchKernelGGL(prep_kernel, dim3(320), dim3(256), 0, stream, Wd, Wu, Wdb, Wub, z, zpart);
  hipLaunchKernelGGL(winscore_kernel, dim3(B_SZ * NWIN), dim3(256), 0, stream, x, zpart, score);
  hipLaunchKernelGGL(fused_win, dim3(B_SZ * TOPK_K), dim3(256), 0, stream,
                     x, score, Wdb, Wub, bd, bu, out);
}

// Round 12
// 108.810 us; speedup vs baseline: 1.5665x; 1.5665x over previous
//
#include <hip/hip_runtime.h>
#include <hip/hip_bf16.h>

#define C_DIM 256
#define B_SZ 32
#define NS 4096
#define NT_Z 256
#define TOPK_K 32
#define NWIN 64
#define WTOK 64

typedef __attribute__((ext_vector_type(8))) short short8;
typedef __attribute__((ext_vector_type(4))) float f32x4;

static __device__ inline unsigned short f2b(float f) {
  union { float f; unsigned int u; } x; x.f = f;
  unsigned int u = x.u;
  return (unsigned short)((u + 0x7FFFu + ((u >> 16) & 1u)) >> 16);
}
static __device__ inline float b2f(unsigned int h16) {   // low 16 bits = bf16
  union { unsigned int u; float f; } x; x.u = h16 << 16;
  return x.f;
}

// ---------------- kernel 1: weights f32->bf16 (vectorized) + z_max partials -
__global__ void prep_kernel(const float* __restrict__ Wd, const float* __restrict__ Wu,
                            unsigned short* __restrict__ Wdb, unsigned short* __restrict__ Wub,
                            const float* __restrict__ z, float* __restrict__ zpart) {
  int blk = blockIdx.x;
  if (blk < 64) {
    int i = blk * 256 + threadIdx.x;     // float4 id, 16384 per matrix
    float4 a = ((const float4*)Wd)[i];
    float4 c = ((const float4*)Wu)[i];
    ushort4 ha, hc;
    ha.x = f2b(a.x); ha.y = f2b(a.y); ha.z = f2b(a.z); ha.w = f2b(a.w);
    hc.x = f2b(c.x); hc.y = f2b(c.y); hc.z = f2b(c.z); hc.w = f2b(c.w);
    ((ushort4*)Wdb)[i] = ha;
    ((ushort4*)Wub)[i] = hc;
  } else {
    int i = blk - 64;                    // 0..255
    int b = i >> 3, ch = i & 7;
    int c = threadIdx.x;
    const float* p = z + ((size_t)b * NT_Z + ch * 32) * C_DIM + c;
    float m = p[0];
    for (int n = 1; n < 32; ++n) m = fmaxf(m, p[(size_t)n * C_DIM]);
    zpart[(size_t)i * C_DIM + c] = m;
  }
}

// ---------------- kernel 2: window scores (+ zmax final reduce) -------------
__global__ __launch_bounds__(256) void winscore_kernel(const float* __restrict__ x,
                                                       const float* __restrict__ zpart,
                                                       float* __restrict__ score) {
  int b = blockIdx.x >> 6;
  int w = blockIdx.x & 63;
  int wy = w >> 3, wx = w & 7;

  __shared__ float zs[C_DIM];
  {
    float m = zpart[(size_t)(b * 8) * C_DIM + threadIdx.x];
    #pragma unroll
    for (int ch = 1; ch < 8; ++ch)
      m = fmaxf(m, zpart[(size_t)(b * 8 + ch) * C_DIM + threadIdx.x]);
    zs[threadIdx.x] = m;
  }
  __syncthreads();

  int wv = threadIdx.x >> 6;
  int ln = threadIdx.x & 63;

  float a0 = 0.f, a1 = 0.f, a2 = 0.f, a3 = 0.f;
  for (int t = 0; t < 16; ++t) {
    int tok = wv * 16 + t;
    int iy = tok >> 3, ix = tok & 7;
    int n = (wy * 8 + iy) * 64 + wx * 8 + ix;
    const float4 v = *(const float4*)(x + ((size_t)b * NS + n) * C_DIM + ln * 4);
    a0 += v.x; a1 += v.y; a2 += v.z; a3 += v.w;
  }
  const float4 z4 = ((const float4*)zs)[ln];
  float p = a0 * z4.x + a1 * z4.y + a2 * z4.z + a3 * z4.w;
  for (int off = 32; off >= 1; off >>= 1) p += __shfl_xor(p, off);

  __shared__ float wsum[4];
  if (ln == 0) wsum[wv] = p;
  __syncthreads();
  if (threadIdx.x == 0) score[blockIdx.x] = wsum[0] + wsum[1] + wsum[2] + wsum[3];
}

// ---------------- kernel 3: top-32 of 64, jax.lax.top_k order ----------------
__global__ void topk_kernel(const float* __restrict__ score, int* __restrict__ idx) {
  int b = blockIdx.x;
  int w = threadIdx.x;  // 64 threads
  __shared__ float s[NWIN];
  float v = score[b * NWIN + w];
  s[w] = v;
  __syncthreads();
  int rank = 0;
  for (int j = 0; j < NWIN; ++j) {
    float sj = s[j];
    rank += (sj > v) || (sj == v && j < w);
  }
  if (rank < TOPK_K) idx[b * TOPK_K + rank] = w;
}

// ---------------- kernel 4 (F1): gather + GEMM1, t -> upper half of out[bk] -
// one block per (b,k), 256 thr / 4 waves, ONE 32 KB LDS buffer.
// (256,4): <=128 combined regs (acc 64 AGPR + ~50 VGPR), 4 blocks/CU.
// t (bf16, +bd, swizzle-transposed through LDS) stored at out_bytes +
// bk*65536 + 32768 (32 KB) -- d_out doubles as scratch, F2 overwrites later.
// XOR swizzle: byte_in_row ^= (row & 7) << 4.
__global__ __launch_bounds__(256, 4) void gemm1_win(
    const float* __restrict__ x, const int* __restrict__ idx,
    const unsigned short* __restrict__ Wdb, const float* __restrict__ bd,
    float* __restrict__ out)
{
  __shared__ unsigned short xe_s[WTOK * C_DIM];  // 32 KB (xe, then t)

  const int bk = blockIdx.x;
  const int b = bk >> 5;
  const int tid = threadIdx.x;
  const int wsel = idx[bk];
  const int wy = wsel >> 3, wx = wsel & 7;

  const int wv = tid >> 6;
  const int ln = tid & 63;
  const int lr = ln & 15;
  const int lg = ln >> 4;
  const int c4 = tid & 63;
  const int m0w = tid >> 6;

  // ---- stage xe (bf16, swizzled), two batches of 8 rows/thread ----
  {
    const float* xb = x + (size_t)b * NS * C_DIM + c4 * 4;
    #pragma unroll
    for (int h = 0; h < 2; ++h) {
      float4 xv[8];
      #pragma unroll
      for (int i = 0; i < 8; ++i) {
        int m = m0w + (h * 8 + i) * 4;
        int n = (wy * 8 + (m >> 3)) * 64 + wx * 8 + (m & 7);
        xv[i] = *(const float4*)(xb + (size_t)n * C_DIM);
      }
      #pragma unroll
      for (int i = 0; i < 8; ++i) {
        int m = m0w + (h * 8 + i) * 4;
        ushort4 hs;
        hs.x = f2b(xv[i].x); hs.y = f2b(xv[i].y); hs.z = f2b(xv[i].z); hs.w = f2b(xv[i].w);
        int byteoff = m * 512 + ((c4 * 8) ^ ((m & 7) << 4));
        *(ushort4*)((char*)xe_s + byteoff) = hs;
      }
    }
  }
  __syncthreads();

  // ---- GEMM1: t = xe @ Wd^T (per-ks weight loads, compiler pipelines) ----
  const unsigned short* wdbase = Wdb + (size_t)(wv * 64 + lr) * C_DIM + lg * 8;
  f32x4 acc[4][4];
  #pragma unroll
  for (int a = 0; a < 4; ++a)
    #pragma unroll
    for (int n2 = 0; n2 < 4; ++n2) acc[a][n2] = (f32x4){0.f, 0.f, 0.f, 0.f};

  #pragma unroll
  for (int ks = 0; ks < 8; ++ks) {
    short8 bf[4];
    #pragma unroll
    for (int nt = 0; nt < 4; ++nt)
      bf[nt] = *(const short8*)(wdbase + nt * 16 * C_DIM + ks * 32);
    const int kb = ks * 64 + lg * 16;
    short8 af[4];
    #pragma unroll
    for (int mt = 0; mt < 4; ++mt) {
      int m = mt * 16 + lr;
      af[mt] = *(const short8*)((const char*)xe_s + m * 512 + (kb ^ ((m & 7) << 4)));
    }
    #pragma unroll
    for (int mt = 0; mt < 4; ++mt)
      #pragma unroll
      for (int nt = 0; nt < 4; ++nt)
        acc[mt][nt] = __builtin_amdgcn_mfma_f32_16x16x32_bf16(af[mt], bf[nt], acc[mt][nt], 0, 0, 0);
  }
  __syncthreads();   // xe reads done; reuse buffer for t

  // ---- t = acc + bd -> bf16 -> LDS (swizzled transpose) ----
  #pragma unroll
  for (int nt = 0; nt < 4; ++nt) {
    int o = wv * 64 + nt * 16 + lr;
    float bdv = bd[o];
    #pragma unroll
    for (int mt = 0; mt < 4; ++mt) {
      #pragma unroll
      for (int r = 0; r < 4; ++r) {
        int m = mt * 16 + lg * 4 + r;
        *(unsigned short*)((char*)xe_s + m * 512 + ((o * 2) ^ ((m & 7) << 4))) = f2b(acc[mt][nt][r] + bdv);
      }
    }
  }
  __syncthreads();

  // ---- coalesced t store: rows linear bf16 into out[bk] upper half ----
  {
    char* tb = (char*)out + (size_t)bk * 65536 + 32768;
    #pragma unroll
    for (int i = 0; i < 16; ++i) {
      int m = m0w + i * 4;
      ushort4 v = *(const ushort4*)((const char*)xe_s + m * 512 + ((c4 * 8) ^ ((m & 7) << 4)));
      *(ushort4*)(tb + m * 512 + c4 * 8) = v;
    }
  }
}

// ---------------- kernel 5 (F2): t -> shift-GEMM2 -> out = x + up + bu ------
// one block per (b,k).  Stages t (coalesced 32 KB) into LDS, GEMM2 with the
// per-group shift on A-reads, then writes full f32 rows with the residual
// re-read from x (f32-exact) and bu.  4 blocks/CU.
__global__ __launch_bounds__(256, 4) void gemm2_win(
    const float* __restrict__ x, const int* __restrict__ idx,
    const unsigned short* __restrict__ Wub, const float* __restrict__ bu,
    float* __restrict__ out)
{
  __shared__ unsigned short t_s[WTOK * C_DIM];  // 32 KB (t, then up)

  const int bk = blockIdx.x;
  const int b = bk >> 5;
  const int tid = threadIdx.x;
  const int wsel = idx[bk];
  const int wy = wsel >> 3, wx = wsel & 7;

  const int wv = tid >> 6;
  const int ln = tid & 63;
  const int lr = ln & 15;
  const int lg = ln >> 4;
  const int c4 = tid & 63;
  const int m0w = tid >> 6;

  // ---- stage t: coalesced 16B loads -> LDS swizzled ----
  {
    const char* tb = (const char*)out + (size_t)bk * 65536 + 32768;
    const int r0 = tid >> 5;        // 8 rows per pass
    const int c8 = tid & 31;        // 16B chunk in row
    #pragma unroll
    for (int j = 0; j < 8; ++j) {
      int r = r0 + j * 8;
      short8 v = *(const short8*)(tb + r * 512 + c8 * 16);
      *(short8*)((char*)t_s + r * 512 + ((c8 * 16) ^ ((r & 7) << 4))) = v;
    }
  }
  __syncthreads();

  // ---- GEMM2: up = shift(t) @ Wu^T ----
  const unsigned short* wubase = Wub + (size_t)(wv * 64 + lr) * C_DIM + lg * 8;
  f32x4 acc2[4][4];
  #pragma unroll
  for (int a = 0; a < 4; ++a)
    #pragma unroll
    for (int n2 = 0; n2 < 4; ++n2) acc2[a][n2] = (f32x4){0.f, 0.f, 0.f, 0.f};

  #pragma unroll
  for (int ks = 0; ks < 8; ++ks) {
    short8 bf[4];
    #pragma unroll
    for (int nt = 0; nt < 4; ++nt)
      bf[nt] = *(const short8*)(wubase + nt * 16 * C_DIM + ks * 32);
    const int g = ks >> 1;              // channel group (64-wide), uniform per ks
    const int dd = ((g & 1) ? -1 : 1) * ((g & 2) ? 8 : 1);
    const int kb = ks * 64 + lg * 16;
    short8 af[4];
    #pragma unroll
    for (int mt = 0; mt < 4; ++mt) {
      int m = mt * 16 + lr;
      int pos = (g & 2) ? (m >> 3) : (m & 7);
      bool ok = (g & 1) ? (pos > 0) : (pos < 7);
      int ms = m + dd;
      ms = ms < 0 ? 0 : (ms > 63 ? 63 : ms);   // safe address, result masked
      short8 v = *(const short8*)((const char*)t_s + ms * 512 + (kb ^ ((ms & 7) << 4)));
      const short8 zed = {0, 0, 0, 0, 0, 0, 0, 0};
      af[mt] = ok ? v : zed;
    }
    #pragma unroll
    for (int mt = 0; mt < 4; ++mt)
      #pragma unroll
      for (int nt = 0; nt < 4; ++nt)
        acc2[mt][nt] = __builtin_amdgcn_mfma_f32_16x16x32_bf16(af[mt], bf[nt], acc2[mt][nt], 0, 0, 0);
  }
  __syncthreads();   // t reads done; reuse buffer for up

  // ---- up -> bf16 -> LDS (swizzled transpose) ----
  #pragma unroll
  for (int nt = 0; nt < 4; ++nt) {
    int c = wv * 64 + nt * 16 + lr;
    #pragma unroll
    for (int mt = 0; mt < 4; ++mt) {
      #pragma unroll
      for (int r = 0; r < 4; ++r) {
        int m = mt * 16 + lg * 4 + r;
        *(unsigned short*)((char*)t_s + m * 512 + ((c * 2) ^ ((m & 7) << 4))) = f2b(acc2[mt][nt][r]);
      }
    }
  }
  __syncthreads();

  // ---- final: out = x(f32 residual) + up + bu, full-row f32 stores ----
  {
    const float4 bu4 = *(const float4*)(bu + c4 * 4);
    const float* xb = x + (size_t)b * NS * C_DIM + c4 * 4;
    float* ob = out + (size_t)bk * WTOK * C_DIM + c4 * 4;
    #pragma unroll
    for (int i = 0; i < 16; ++i) {
      int m = m0w + i * 4;
      int n = (wy * 8 + (m >> 3)) * 64 + wx * 8 + (m & 7);
      float4 xr = *(const float4*)(xb + (size_t)n * C_DIM);
      ushort4 u4 = *(const ushort4*)((const char*)t_s + m * 512 + ((c4 * 8) ^ ((m & 7) << 4)));
      float4 o;
      o.x = xr.x + b2f(u4.x) + bu4.x;
      o.y = xr.y + b2f(u4.y) + bu4.y;
      o.z = xr.z + b2f(u4.z) + bu4.z;
      o.w = xr.w + b2f(u4.w) + bu4.w;
      *(float4*)(ob + (size_t)m * C_DIM) = o;
    }
  }
}

// ---------------- launch ----------------
extern "C" void kernel_launch(void* const* d_in, const int* in_sizes, int n_in,
                              void* d_out, int out_size, void* d_ws, size_t ws_size,
                              hipStream_t stream) {
  const float* z  = (const float*)d_in[0];
  const float* x  = (const float*)d_in[1];
  const float* Wd = (const float*)d_in[2];
  const float* bd = (const float*)d_in[3];
  const float* Wu = (const float*)d_in[4];
  const float* bu = (const float*)d_in[5];
  float* out = (float*)d_out;

  char* ws = (char*)d_ws;
  unsigned short* Wdb = (unsigned short*)(ws);            // 0      .. 131072
  unsigned short* Wub = (unsigned short*)(ws + 131072);   // 131072 .. 262144
  float* zpart = (float*)(ws + 262144);                   // 262144 .. 524288 (32*8*256 f32)
  float* score = (float*)(ws + 524288);                   // 524288 .. 532480
  int*   idx   = (int*)(ws + 532480);                     // 532480 .. 536576

  hipLaunchKernelGGL(prep_kernel, dim3(320), dim3(256), 0, stream, Wd, Wu, Wdb, Wub, z, zpart);
  hipLaunchKernelGGL(winscore_kernel, dim3(B_SZ * NWIN), dim3(256), 0, stream, x, zpart, score);
  hipLaunchKernelGGL(topk_kernel, dim3(B_SZ), dim3(NWIN), 0, stream, score, idx);
  hipLaunchKernelGGL(gemm1_win, dim3(B_SZ * TOPK_K), dim3(256), 0, stream, x, idx, Wdb, bd, out);
  hipLaunchKernelGGL(gemm2_win, dim3(B_SZ * TOPK_K), dim3(256), 0, stream, x, idx, Wub, bu, out);
}

// Round 13
// 85.212 us; speedup vs baseline: 2.0003x; 1.2769x over previous
//
#include <hip/hip_runtime.h>
#include <hip/hip_bf16.h>

#define C_DIM 256
#define B_SZ 32
#define NS 4096
#define NT_Z 256
#define TOPK_K 32
#define NWIN 64
#define WTOK 64

typedef __attribute__((ext_vector_type(8))) short short8;
typedef __attribute__((ext_vector_type(4))) float f32x4;

static __device__ inline unsigned short f2b(float f) {
  union { float f; unsigned int u; } x; x.f = f;
  unsigned int u = x.u;
  return (unsigned short)((u + 0x7FFFu + ((u >> 16) & 1u)) >> 16);
}
static __device__ inline float b2f(unsigned int h16) {   // low 16 bits = bf16
  union { unsigned int u; float f; } x; x.u = h16 << 16;
  return x.f;
}

// ---------------- kernel 1: weights f32->bf16 (vectorized) + z_max partials -
__global__ void prep_kernel(const float* __restrict__ Wd, const float* __restrict__ Wu,
                            unsigned short* __restrict__ Wdb, unsigned short* __restrict__ Wub,
                            const float* __restrict__ z, float* __restrict__ zpart) {
  int blk = blockIdx.x;
  if (blk < 64) {
    int i = blk * 256 + threadIdx.x;     // float4 id, 16384 per matrix
    float4 a = ((const float4*)Wd)[i];
    float4 c = ((const float4*)Wu)[i];
    ushort4 ha, hc;
    ha.x = f2b(a.x); ha.y = f2b(a.y); ha.z = f2b(a.z); ha.w = f2b(a.w);
    hc.x = f2b(c.x); hc.y = f2b(c.y); hc.z = f2b(c.z); hc.w = f2b(c.w);
    ((ushort4*)Wdb)[i] = ha;
    ((ushort4*)Wub)[i] = hc;
  } else {
    int i = blk - 64;                    // 0..255
    int b = i >> 3, ch = i & 7;
    int c = threadIdx.x;
    const float* p = z + ((size_t)b * NT_Z + ch * 32) * C_DIM + c;
    float m = p[0];
    for (int n = 1; n < 32; ++n) m = fmaxf(m, p[(size_t)n * C_DIM]);
    zpart[(size_t)i * C_DIM + c] = m;
  }
}

// ---------------- kernel 2: window scores (+ zmax final reduce) -------------
__global__ __launch_bounds__(256) void winscore_kernel(const float* __restrict__ x,
                                                       const float* __restrict__ zpart,
                                                       float* __restrict__ score) {
  int b = blockIdx.x >> 6;
  int w = blockIdx.x & 63;
  int wy = w >> 3, wx = w & 7;

  __shared__ float zs[C_DIM];
  {
    float m = zpart[(size_t)(b * 8) * C_DIM + threadIdx.x];
    #pragma unroll
    for (int ch = 1; ch < 8; ++ch)
      m = fmaxf(m, zpart[(size_t)(b * 8 + ch) * C_DIM + threadIdx.x]);
    zs[threadIdx.x] = m;
  }
  __syncthreads();

  int wv = threadIdx.x >> 6;
  int ln = threadIdx.x & 63;

  float a0 = 0.f, a1 = 0.f, a2 = 0.f, a3 = 0.f;
  for (int t = 0; t < 16; ++t) {
    int tok = wv * 16 + t;
    int iy = tok >> 3, ix = tok & 7;
    int n = (wy * 8 + iy) * 64 + wx * 8 + ix;
    const float4 v = *(const float4*)(x + ((size_t)b * NS + n) * C_DIM + ln * 4);
    a0 += v.x; a1 += v.y; a2 += v.z; a3 += v.w;
  }
  const float4 z4 = ((const float4*)zs)[ln];
  float p = a0 * z4.x + a1 * z4.y + a2 * z4.z + a3 * z4.w;
  for (int off = 32; off >= 1; off >>= 1) p += __shfl_xor(p, off);

  __shared__ float wsum[4];
  if (ln == 0) wsum[wv] = p;
  __syncthreads();
  if (threadIdx.x == 0) score[blockIdx.x] = wsum[0] + wsum[1] + wsum[2] + wsum[3];
}

// ---------------- kernel 3: fused topk + gather + GEMM1 + shift + GEMM2 ----
// 16-waves-per-CU WITH ILP: 512 thr / 8 waves; wave owns 64x32 output
// (acc[4][2] = 32 AGPR).  Single 32 KB LDS buffer (xe -> t -> sum); residual
// folded into acc2 C-init (16 regs); depth-2 rolling weight prefetch (16
// regs); staging 8-deep.  Peak ~100 combined regs <= 128 cap of (512,4)
// -> 2 blocks x 8 waves = 16 waves/CU, pipeline intact.
// XOR swizzle: byte_in_row ^= (row & 7) << 4.
__global__ __launch_bounds__(512, 4) void fused_win(
    const float* __restrict__ x, const float* __restrict__ score,
    const unsigned short* __restrict__ Wdb, const unsigned short* __restrict__ Wub,
    const float* __restrict__ bd, const float* __restrict__ bu,
    float* __restrict__ out)
{
  __shared__ unsigned short buf[WTOK * C_DIM];  // 32 KB (xe, then t, then sum)
  __shared__ float sc[NWIN];
  __shared__ int wsel_s;

  const int bk = blockIdx.x;
  const int b = bk >> 5;
  const int kk = bk & 31;
  const int tid = threadIdx.x;

  // ---- in-block top-k rank select (reproduces jax.lax.top_k order) ----
  if (tid < NWIN) sc[tid] = score[b * NWIN + tid];
  __syncthreads();
  if (tid < NWIN) {
    float v = sc[tid];
    int rank = 0;
    #pragma unroll
    for (int j = 0; j < NWIN; ++j) {
      float sj = sc[j];
      rank += (sj > v) || (sj == v && j < tid);
    }
    if (rank == kk) wsel_s = tid;
  }
  __syncthreads();
  const int wsel = wsel_s;
  const int wy = wsel >> 3, wx = wsel & 7;

  const int wv = tid >> 6;   // 0..7
  const int ln = tid & 63;
  const int lr = ln & 15;    // A-row / B-col / D-col
  const int lg = ln >> 4;    // k-subgroup
  const int c4 = tid & 63;   // float4 column for staging/output
  const int m0w = tid >> 6;  // starting row (0..7) for staging/output

  const unsigned short* wdbase = Wdb + (size_t)(wv * 32 + lr) * C_DIM + lg * 8;
  const unsigned short* wubase = Wub + (size_t)(wv * 32 + lr) * C_DIM + lg * 8;

  // ---- GEMM1 weight prologue (depth 2; land during staging) ----
  short8 wq[2][2];
  #pragma unroll
  for (int p = 0; p < 2; ++p)
    #pragma unroll
    for (int nt = 0; nt < 2; ++nt)
      wq[p][nt] = *(const short8*)(wdbase + nt * 16 * C_DIM + p * 32);

  // bias regs
  float bdv[2], buv[2];
  #pragma unroll
  for (int nt = 0; nt < 2; ++nt) {
    bdv[nt] = bd[wv * 32 + nt * 16 + lr];
    buv[nt] = bu[wv * 32 + nt * 16 + lr];
  }

  // ---- stage xe (bf16, swizzled): 8 loads in flight ----
  {
    const float* xb = x + (size_t)b * NS * C_DIM + c4 * 4;
    float4 xv[8];
    #pragma unroll
    for (int i = 0; i < 8; ++i) {
      int m = m0w + i * 8;
      int n = (wy * 8 + (m >> 3)) * 64 + wx * 8 + (m & 7);
      xv[i] = *(const float4*)(xb + (size_t)n * C_DIM);
    }
    #pragma unroll
    for (int i = 0; i < 8; ++i) {
      int m = m0w + i * 8;
      ushort4 hs;
      hs.x = f2b(xv[i].x); hs.y = f2b(xv[i].y); hs.z = f2b(xv[i].z); hs.w = f2b(xv[i].w);
      int byteoff = m * 512 + ((c4 * 8) ^ ((m & 7) << 4));
      *(ushort4*)((char*)buf + byteoff) = hs;
    }
  }
  __syncthreads();   // B1: xe ready

  // ---- GEMM1: t = xe @ Wd^T (rolling depth-2 weight prefetch) ----
  f32x4 acc[4][2];
  #pragma unroll
  for (int a = 0; a < 4; ++a)
    #pragma unroll
    for (int n2 = 0; n2 < 2; ++n2) acc[a][n2] = (f32x4){0.f, 0.f, 0.f, 0.f};

  #pragma unroll
  for (int ks = 0; ks < 8; ++ks) {
    const int slot = ks & 1;
    const int kb = ks * 64 + lg * 16;
    short8 af[4];
    #pragma unroll
    for (int mt = 0; mt < 4; ++mt) {
      int m = mt * 16 + lr;
      af[mt] = *(const short8*)((const char*)buf + m * 512 + (kb ^ ((m & 7) << 4)));
    }
    __builtin_amdgcn_s_setprio(1);
    #pragma unroll
    for (int mt = 0; mt < 4; ++mt)
      #pragma unroll
      for (int nt = 0; nt < 2; ++nt)
        acc[mt][nt] = __builtin_amdgcn_mfma_f32_16x16x32_bf16(af[mt], wq[slot][nt], acc[mt][nt], 0, 0, 0);
    __builtin_amdgcn_s_setprio(0);
    if (ks + 2 < 8) {
      #pragma unroll
      for (int nt = 0; nt < 2; ++nt)
        wq[slot][nt] = *(const short8*)(wdbase + nt * 16 * C_DIM + (ks + 2) * 32);
    }
  }

  // ---- capture residual xe (MFMA C/D layout) into 16 packed regs ----
  unsigned int res[4][2][2];
  #pragma unroll
  for (int mt = 0; mt < 4; ++mt) {
    #pragma unroll
    for (int nt = 0; nt < 2; ++nt) {
      int c = wv * 32 + nt * 16 + lr;
      #pragma unroll
      for (int j = 0; j < 2; ++j) {
        int m0 = mt * 16 + lg * 4 + 2 * j;
        unsigned int lo = *(const unsigned short*)((const char*)buf + m0 * 512 + ((c * 2) ^ ((m0 & 7) << 4)));
        unsigned int hi = *(const unsigned short*)((const char*)buf + (m0 + 1) * 512 + ((c * 2) ^ (((m0 + 1) & 7) << 4)));
        res[mt][nt][j] = lo | (hi << 16);
      }
    }
  }

  // ---- GEMM2 weight prologue (lands under epi1 + barrier) ----
  short8 wq2[2][2];
  #pragma unroll
  for (int p = 0; p < 2; ++p)
    #pragma unroll
    for (int nt = 0; nt < 2; ++nt)
      wq2[p][nt] = *(const short8*)(wubase + nt * 16 * C_DIM + p * 32);

  __syncthreads();   // B2: all xe reads done, buf free for t

  // ---- epi1: t = acc + bd -> bf16 -> buf (swizzled) ----
  #pragma unroll
  for (int nt = 0; nt < 2; ++nt) {
    int o = wv * 32 + nt * 16 + lr;
    #pragma unroll
    for (int mt = 0; mt < 4; ++mt) {
      #pragma unroll
      for (int r = 0; r < 4; ++r) {
        int m = mt * 16 + lg * 4 + r;
        *(unsigned short*)((char*)buf + m * 512 + ((o * 2) ^ ((m & 7) << 4))) = f2b(acc[mt][nt][r] + bdv[nt]);
      }
    }
  }
  __syncthreads();   // B3: t ready

  // ---- acc2 init = xe + bu (res dies here) ----
  f32x4 acc2[4][2];
  #pragma unroll
  for (int mt = 0; mt < 4; ++mt) {
    #pragma unroll
    for (int nt = 0; nt < 2; ++nt) {
      acc2[mt][nt][0] = b2f(res[mt][nt][0] & 0xffffu) + buv[nt];
      acc2[mt][nt][1] = b2f(res[mt][nt][0] >> 16)     + buv[nt];
      acc2[mt][nt][2] = b2f(res[mt][nt][1] & 0xffffu) + buv[nt];
      acc2[mt][nt][3] = b2f(res[mt][nt][1] >> 16)     + buv[nt];
    }
  }

  // ---- GEMM2: acc2 += shift(t) @ Wu^T (rolling depth-2 prefetch) ----
  #pragma unroll
  for (int ks = 0; ks < 8; ++ks) {
    const int slot = ks & 1;
    const int g = ks >> 1;              // channel group (64-wide), uniform per ks
    const int dd = ((g & 1) ? -1 : 1) * ((g & 2) ? 8 : 1);
    const int kb = ks * 64 + lg * 16;
    short8 af[4];
    #pragma unroll
    for (int mt = 0; mt < 4; ++mt) {
      int m = mt * 16 + lr;
      int pos = (g & 2) ? (m >> 3) : (m & 7);
      bool ok = (g & 1) ? (pos > 0) : (pos < 7);
      int ms = m + dd;
      ms = ms < 0 ? 0 : (ms > 63 ? 63 : ms);   // safe address, result masked
      short8 v = *(const short8*)((const char*)buf + ms * 512 + (kb ^ ((ms & 7) << 4)));
      const short8 zed = {0, 0, 0, 0, 0, 0, 0, 0};
      af[mt] = ok ? v : zed;
    }
    __builtin_amdgcn_s_setprio(1);
    #pragma unroll
    for (int mt = 0; mt < 4; ++mt)
      #pragma unroll
      for (int nt = 0; nt < 2; ++nt)
        acc2[mt][nt] = __builtin_amdgcn_mfma_f32_16x16x32_bf16(af[mt], wq2[slot][nt], acc2[mt][nt], 0, 0, 0);
    __builtin_amdgcn_s_setprio(0);
    if (ks + 2 < 8) {
      #pragma unroll
      for (int nt = 0; nt < 2; ++nt)
        wq2[slot][nt] = *(const short8*)(wubase + nt * 16 * C_DIM + (ks + 2) * 32);
    }
  }
  __syncthreads();   // B4: all t reads done, buf free for sum

  // ---- epi2a: buf = f2b(acc2)  (acc2 = xe + up + bu) ----
  #pragma unroll
  for (int nt = 0; nt < 2; ++nt) {
    int c = wv * 32 + nt * 16 + lr;
    #pragma unroll
    for (int mt = 0; mt < 4; ++mt) {
      #pragma unroll
      for (int r = 0; r < 4; ++r) {
        int m = mt * 16 + lg * 4 + r;
        *(unsigned short*)((char*)buf + m * 512 + ((c * 2) ^ ((m & 7) << 4))) = f2b(acc2[mt][nt][r]);
      }
    }
  }
  __syncthreads();   // B5

  // ---- epi2b: coalesced full-row f32 stores ----
  {
    float* ob = out + (size_t)bk * WTOK * C_DIM + c4 * 4;
    #pragma unroll
    for (int i = 0; i < 8; ++i) {
      int m = m0w + i * 8;
      int off = m * 512 + ((c4 * 8) ^ ((m & 7) << 4));
      ushort4 s4 = *(const ushort4*)((const char*)buf + off);
      float4 o;
      o.x = b2f(s4.x); o.y = b2f(s4.y); o.z = b2f(s4.z); o.w = b2f(s4.w);
      *(float4*)(ob + (size_t)m * C_DIM) = o;
    }
  }
}

// ---------------- launch ----------------
extern "C" void kernel_launch(void* const* d_in, const int* in_sizes, int n_in,
                              void* d_out, int out_size, void* d_ws, size_t ws_size,
                              hipStream_t stream) {
  const float* z  = (const float*)d_in[0];
  const float* x  = (const float*)d_in[1];
  const float* Wd = (const float*)d_in[2];
  const float* bd = (const float*)d_in[3];
  const float* Wu = (const float*)d_in[4];
  const float* bu = (const float*)d_in[5];
  float* out = (float*)d_out;

  char* ws = (char*)d_ws;
  unsigned short* Wdb = (unsigned short*)(ws);            // 0      .. 131072
  unsigned short* Wub = (unsigned short*)(ws + 131072);   // 131072 .. 262144
  float* zpart = (float*)(ws + 262144);                   // 262144 .. 524288 (32*8*256 f32)
  float* score = (float*)(ws + 524288);                   // 524288 .. 532480

  hipLaunchKernelGGL(prep_kernel, dim3(320), dim3(256), 0, stream, Wd, Wu, Wdb, Wub, z, zpart);
  hipLaunchKernelGGL(winscore_kernel, dim3(B_SZ * NWIN), dim3(256), 0, stream, x, zpart, score);
  hipLaunchKernelGGL(fused_win, dim3(B_SZ * TOPK_K), dim3(512), 0, stream,
                     x, score, Wdb, Wub, bd, bu, out);
}